// Round 2
// 639.093 us; speedup vs baseline: 1.2921x; 1.2921x over previous
//
#include <hip/hip_runtime.h>
#include <hip/hip_bf16.h>
#include <math.h>

typedef __attribute__((ext_vector_type(8))) short short8;
typedef __attribute__((ext_vector_type(4))) float f32x4;

__device__ __forceinline__ float sigm(float v) { return 1.0f / (1.0f + expf(-v)); }
__device__ __forceinline__ unsigned short f2b(float f) {
  __hip_bfloat16 h = __float2bfloat16(f);
  return __builtin_bit_cast(unsigned short, h);
}

// ---------------------------------------------------------------------------
// K0: pre-convert eW1[:, :2048] -> Wb1 bf16 [128][2048], dW4 -> Wb4 bf16 [2048][128]
// ---------------------------------------------------------------------------
__global__ __launch_bounds__(256) void wcvt_kernel(
    const float* __restrict__ eW1, const float* __restrict__ dW4,
    unsigned short* __restrict__ Wb1, unsigned short* __restrict__ Wb4)
{
  int idx = blockIdx.x * 256 + threadIdx.x;   // 0..262143
  int o = idx >> 11, k = idx & 2047;
  Wb1[idx] = f2b(eW1[(size_t)o * 2049 + k]);
  Wb4[idx] = f2b(dW4[idx]);
}

// ---------------------------------------------------------------------------
// K1: MFMA dual GEMM: accx = x@W.T, accd = xd@W.T (bf16, fp32 acc)
// v2: no LDS, no barriers. Per-lane direct fragment loads (A from fp32 x/xd
// with in-register bf16 pack; B from bf16 Wb, L2-resident). BM=16 -> 1024
// blocks (4/CU) for latency hiding. Each wave owns 32 output cols.
// ---------------------------------------------------------------------------
__global__ __launch_bounds__(256, 2) void enc1_mfma(
    const float* __restrict__ x, const float* __restrict__ xd,
    const float* __restrict__ tr, const unsigned short* __restrict__ Wb,
    const float* __restrict__ Wfull, const float* __restrict__ bias,
    float* __restrict__ a1, float* __restrict__ dz1)
{
  const int t = threadIdx.x;
  const int w = t >> 6, L = t & 63, q = L >> 4, ln = L & 15;
  const int r0 = blockIdx.x * 16;
  const size_t rowA  = (size_t)(r0 + ln) * 2048;
  const size_t rowB0 = (size_t)(w * 32 + ln) * 2048;
  const size_t rowB1 = (size_t)(w * 32 + 16 + ln) * 2048;

  f32x4 accx[2], accd[2];
  accx[0] = accx[1] = (f32x4){0.f, 0.f, 0.f, 0.f};
  accd[0] = accd[1] = (f32x4){0.f, 0.f, 0.f, 0.f};

#pragma unroll 2
  for (int kt = 0; kt < 64; ++kt) {
    const int kb = kt * 32 + q * 8;
    float4 xv0 = *(const float4*)&x [rowA + kb];
    float4 xv1 = *(const float4*)&x [rowA + kb + 4];
    float4 dv0 = *(const float4*)&xd[rowA + kb];
    float4 dv1 = *(const float4*)&xd[rowA + kb + 4];
    short8 bw0 = *(const short8*)&Wb[rowB0 + kb];
    short8 bw1 = *(const short8*)&Wb[rowB1 + kb];
    short8 ax, ad;
    ax[0] = (short)f2b(xv0.x); ax[1] = (short)f2b(xv0.y);
    ax[2] = (short)f2b(xv0.z); ax[3] = (short)f2b(xv0.w);
    ax[4] = (short)f2b(xv1.x); ax[5] = (short)f2b(xv1.y);
    ax[6] = (short)f2b(xv1.z); ax[7] = (short)f2b(xv1.w);
    ad[0] = (short)f2b(dv0.x); ad[1] = (short)f2b(dv0.y);
    ad[2] = (short)f2b(dv0.z); ad[3] = (short)f2b(dv0.w);
    ad[4] = (short)f2b(dv1.x); ad[5] = (short)f2b(dv1.y);
    ad[6] = (short)f2b(dv1.z); ad[7] = (short)f2b(dv1.w);
    accx[0] = __builtin_amdgcn_mfma_f32_16x16x32_bf16(ax, bw0, accx[0], 0, 0, 0);
    accx[1] = __builtin_amdgcn_mfma_f32_16x16x32_bf16(ax, bw1, accx[1], 0, 0, 0);
    accd[0] = __builtin_amdgcn_mfma_f32_16x16x32_bf16(ad, bw0, accd[0], 0, 0, 0);
    accd[1] = __builtin_amdgcn_mfma_f32_16x16x32_bf16(ad, bw1, accd[1], 0, 0, 0);
  }
  // epilogue: C[row = q*4 + r][col = w*32 + n*16 + ln]
#pragma unroll
  for (int r = 0; r < 4; ++r) {
    const int row = r0 + q * 4 + r;
    const float trv = tr[row];
#pragma unroll
    for (int n = 0; n < 2; ++n) {
      const int col = w * 32 + n * 16 + ln;
      const float wl = Wfull[(size_t)col * 2049 + 2048];
      float p = accx[n][r] + trv * wl + bias[col];
      float g = accd[n][r] + trv * wl;
      float a = sigm(p);
      a1 [(size_t)row * 128 + col] = a;
      dz1[(size_t)row * 128 + col] = a * (1.f - a) * g;
    }
  }
}

// ---------------------------------------------------------------------------
// K2: encoder layers 2-4 + z, z_dot_true, z_dot_pred, per-block partial losses
// ---------------------------------------------------------------------------
__global__ __launch_bounds__(256) void enc_small_kernel(
    const float* __restrict__ a1, const float* __restrict__ dz1,
    const float* __restrict__ W2, const float* __restrict__ b2,
    const float* __restrict__ W3, const float* __restrict__ b3,
    const float* __restrict__ W4, const float* __restrict__ b4,
    const float* __restrict__ coef, const float* __restrict__ size_in,
    const float* __restrict__ treat,
    float* __restrict__ z_out, float* __restrict__ zdp_out,
    float* __restrict__ pe0, float* __restrict__ pe1, float* __restrict__ pe2)
{
  __shared__ float sW2[64 * 129];
  __shared__ float sW3[32 * 65];
  __shared__ float sW4[96];
  __shared__ float sB2[64], sB3[32], sB4[3], sC[21];
  __shared__ float a1s[4 * 128], d1s[4 * 128];
  __shared__ float a2s[4 * 64],  d2s[4 * 64];
  __shared__ float a3s[4 * 32],  d3s[4 * 32];
  __shared__ float zs[12], zds[12];
  __shared__ float rowl[4][3];
  const int t = threadIdx.x;
  for (int i = t; i < 64 * 128; i += 256) sW2[(i >> 7) * 129 + (i & 127)] = W2[i];
  for (int i = t; i < 32 * 64;  i += 256) sW3[(i >> 6) * 65  + (i & 63)]  = W3[i];
  if (t < 96) sW4[t] = W4[t];
  if (t < 64) sB2[t] = b2[t];
  if (t < 32) sB3[t] = b3[t];
  if (t < 3)  sB4[t] = b4[t];
  if (t < 21) sC[t]  = coef[t];
  const int r0 = blockIdx.x * 4;
  for (int i = t; i < 4 * 128; i += 256) {
    a1s[i] = a1 [(size_t)r0 * 128 + i];
    d1s[i] = dz1[(size_t)r0 * 128 + i];
  }
  __syncthreads();
  {
    const int r = t >> 6, o = t & 63;
    float p = 0.f, g = 0.f;
#pragma unroll 8
    for (int k = 0; k < 128; ++k) {
      float w = sW2[o * 129 + k];
      p = fmaf(w, a1s[r * 128 + k], p);
      g = fmaf(w, d1s[r * 128 + k], g);
    }
    float a = sigm(p + sB2[o]);
    a2s[r * 64 + o] = a;
    d2s[r * 64 + o] = a * (1.f - a) * g;
  }
  __syncthreads();
  if (t < 128) {
    const int r = t >> 5, o = t & 31;
    float p = 0.f, g = 0.f;
#pragma unroll
    for (int k = 0; k < 64; ++k) {
      float w = sW3[o * 65 + k];
      p = fmaf(w, a2s[r * 64 + k], p);
      g = fmaf(w, d2s[r * 64 + k], g);
    }
    float a = sigm(p + sB3[o]);
    a3s[r * 32 + o] = a;
    d3s[r * 32 + o] = a * (1.f - a) * g;
  }
  __syncthreads();
  if (t < 12) {
    const int r = t / 3, j = t % 3;
    float p = 0.f, g = 0.f;
#pragma unroll
    for (int k = 0; k < 32; ++k) {
      float w = sW4[j * 32 + k];
      p = fmaf(w, a3s[r * 32 + k], p);
      g = fmaf(w, d3s[r * 32 + k], g);
    }
    float zv = p + sB4[j];
    zs [r * 3 + j] = zv;
    zds[r * 3 + j] = g;
    z_out[(size_t)(r0 + r) * 3 + j] = zv;
  }
  __syncthreads();
  if (t < 4) {
    const int r = t;
    float s = zs[r * 3 + 0], d = zs[r * 3 + 1], tt = zs[r * 3 + 2];
    float th[7] = {1.f, s, s * s, s * d, s * tt, s * s * d, s * s * tt};
    float sz = 0.f;
    for (int j = 0; j < 3; ++j) {
      float zp = 0.f;
#pragma unroll
      for (int i = 0; i < 7; ++i) zp = fmaf(th[i], sC[i * 3 + j], zp);
      zdp_out[(size_t)(r0 + r) * 3 + j] = zp;
      float e = zds[r * 3 + j] - zp;
      sz += e * e;
    }
    float e0 = s - size_in[r0 + r];
    float logit = tt;
    float trv = treat[r0 + r];
    float lt = fmaxf(logit, 0.f) + log1pf(expf(-fabsf(logit))) - logit * trv;
    rowl[r][0] = e0 * e0; rowl[r][1] = lt; rowl[r][2] = sz;
  }
  __syncthreads();
  if (t == 0) {
    float s0 = 0, s1 = 0, s2 = 0;
    for (int r = 0; r < 4; ++r) { s0 += rowl[r][0]; s1 += rowl[r][1]; s2 += rowl[r][2]; }
    pe0[blockIdx.x] = s0;
    pe1[blockIdx.x] = s1;
    pe2[blockIdx.x] = s2;
  }
}

// ---------------------------------------------------------------------------
// K3: decoder layers 1-3 forward + chain derivative -> h3b, g3b (bf16)
// ---------------------------------------------------------------------------
__global__ __launch_bounds__(256) void dec_small_kernel(
    const float* __restrict__ z_in, const float* __restrict__ zdp,
    const float* __restrict__ W1, const float* __restrict__ b1,
    const float* __restrict__ W2, const float* __restrict__ b2,
    const float* __restrict__ W3, const float* __restrict__ b3,
    unsigned short* __restrict__ h3b, unsigned short* __restrict__ g3b)
{
  __shared__ float sW1[96], sB1[32];
  __shared__ float sW2[64 * 33], sB2[64];
  __shared__ float sW3[128 * 65], sB3[128];
  __shared__ float zr[12], zp[12];
  __shared__ float h1s[4 * 32], g1s[4 * 32];
  __shared__ float h2s[4 * 64], g2s[4 * 64];
  const int t = threadIdx.x;
  for (int i = t; i < 64 * 32;  i += 256) sW2[(i >> 5) * 33 + (i & 31)] = W2[i];
  for (int i = t; i < 128 * 64; i += 256) sW3[(i >> 6) * 65 + (i & 63)] = W3[i];
  if (t < 96)  sW1[t] = W1[t];
  if (t < 32)  sB1[t] = b1[t];
  if (t < 64)  sB2[t] = b2[t];
  if (t < 128) sB3[t] = b3[t];
  const int r0 = blockIdx.x * 4;
  if (t < 12) { zr[t] = z_in[(size_t)r0 * 3 + t]; zp[t] = zdp[(size_t)r0 * 3 + t]; }
  __syncthreads();
  if (t < 128) {
    const int r = t >> 5, o = t & 31;
    float p = sB1[o], g = 0.f;
#pragma unroll
    for (int k = 0; k < 3; ++k) {
      float w = sW1[o * 3 + k];
      p = fmaf(w, zr[r * 3 + k], p);
      g = fmaf(w, zp[r * 3 + k], g);
    }
    float h = sigm(p);
    h1s[r * 32 + o] = h; g1s[r * 32 + o] = h * (1.f - h) * g;
  }
  __syncthreads();
  {
    const int r = t >> 6, o = t & 63;
    float p = sB2[o], g = 0.f;
#pragma unroll
    for (int k = 0; k < 32; ++k) {
      float w = sW2[o * 33 + k];
      p = fmaf(w, h1s[r * 32 + k], p);
      g = fmaf(w, g1s[r * 32 + k], g);
    }
    float h = sigm(p);
    h2s[r * 64 + o] = h; g2s[r * 64 + o] = h * (1.f - h) * g;
  }
  __syncthreads();
  {
    const int r = t >> 6;
    const int ob = t & 63;
#pragma unroll
    for (int c = 0; c < 2; ++c) {
      const int o = ob + 64 * c;
      float p = sB3[o], g = 0.f;
#pragma unroll
      for (int k = 0; k < 64; ++k) {
        float w = sW3[o * 65 + k];
        p = fmaf(w, h2s[r * 64 + k], p);
        g = fmaf(w, g2s[r * 64 + k], g);
      }
      float h = sigm(p);
      h3b[(size_t)(r0 + r) * 128 + o] = f2b(h);
      g3b[(size_t)(r0 + r) * 128 + o] = f2b(h * (1.f - h) * g);
    }
  }
}

// ---------------------------------------------------------------------------
// K4: MFMA dual GEMM: xhat = h3@W4.T + b, xdp = g3@W4.T; fused recon/sindy_x.
// v2: no GEMM LDS/barriers (direct per-lane fragment loads, all L1/L2-hot),
// LDS only for the f32 transpose; float4 epilogue; nontemporal xhat stores;
// per-block partial sums (no atomics).
// ---------------------------------------------------------------------------
__global__ __launch_bounds__(256, 2) void dec4_mfma(
    const unsigned short* __restrict__ h3b, const unsigned short* __restrict__ g3b,
    const unsigned short* __restrict__ Wb, const float* __restrict__ bias,
    const float* __restrict__ x, const float* __restrict__ xd,
    float* __restrict__ xhat, float* __restrict__ pr, float* __restrict__ ps)
{
  __shared__ float sH[32 * 132];
  __shared__ float sG[32 * 132];
  __shared__ float red[8];
  const int t = threadIdx.x, w = t >> 6, L = t & 63, q = L >> 4, ln = L & 15;
  const int r0 = blockIdx.x * 32, c0 = blockIdx.y * 128;

  f32x4 accH[2][2], accG[2][2];
#pragma unroll
  for (int m = 0; m < 2; ++m)
#pragma unroll
    for (int n = 0; n < 2; ++n) {
      accH[m][n] = (f32x4){0.f, 0.f, 0.f, 0.f};
      accG[m][n] = (f32x4){0.f, 0.f, 0.f, 0.f};
    }

  const size_t a0 = (size_t)(r0 + ln) * 128;
  const size_t a1r = (size_t)(r0 + 16 + ln) * 128;
  const size_t b0 = (size_t)(c0 + w * 32 + ln) * 128;
  const size_t b1 = (size_t)(c0 + w * 32 + 16 + ln) * 128;

#pragma unroll
  for (int ks = 0; ks < 4; ++ks) {
    const int kb = ks * 32 + q * 8;
    short8 ah0 = *(const short8*)&h3b[a0 + kb];
    short8 ah1 = *(const short8*)&h3b[a1r + kb];
    short8 ag0 = *(const short8*)&g3b[a0 + kb];
    short8 ag1 = *(const short8*)&g3b[a1r + kb];
    short8 bw0 = *(const short8*)&Wb[b0 + kb];
    short8 bw1 = *(const short8*)&Wb[b1 + kb];
    accH[0][0] = __builtin_amdgcn_mfma_f32_16x16x32_bf16(ah0, bw0, accH[0][0], 0, 0, 0);
    accH[0][1] = __builtin_amdgcn_mfma_f32_16x16x32_bf16(ah0, bw1, accH[0][1], 0, 0, 0);
    accH[1][0] = __builtin_amdgcn_mfma_f32_16x16x32_bf16(ah1, bw0, accH[1][0], 0, 0, 0);
    accH[1][1] = __builtin_amdgcn_mfma_f32_16x16x32_bf16(ah1, bw1, accH[1][1], 0, 0, 0);
    accG[0][0] = __builtin_amdgcn_mfma_f32_16x16x32_bf16(ag0, bw0, accG[0][0], 0, 0, 0);
    accG[0][1] = __builtin_amdgcn_mfma_f32_16x16x32_bf16(ag0, bw1, accG[0][1], 0, 0, 0);
    accG[1][0] = __builtin_amdgcn_mfma_f32_16x16x32_bf16(ag1, bw0, accG[1][0], 0, 0, 0);
    accG[1][1] = __builtin_amdgcn_mfma_f32_16x16x32_bf16(ag1, bw1, accG[1][1], 0, 0, 0);
  }

  // transpose accumulators to row-major f32 tiles in LDS
#pragma unroll
  for (int m = 0; m < 2; ++m)
#pragma unroll
    for (int n = 0; n < 2; ++n)
#pragma unroll
      for (int r = 0; r < 4; ++r) {
        const int rr = m * 16 + q * 4 + r;
        const int cc = w * 32 + n * 16 + ln;
        sH[rr * 132 + cc] = accH[m][n][r];
        sG[rr * 132 + cc] = accG[m][n][r];
      }
  __syncthreads();

  // vectorized epilogue: thread t owns row (t>>3), cols (t&7)*4 + j*32
  const int row = t >> 3;
  const int cb = (t & 7) * 4;
  const size_t gbase = (size_t)(r0 + row) * 2048 + c0 + cb;
  float rsum = 0.f, ssum = 0.f;
#pragma unroll
  for (int j = 0; j < 4; ++j) {
    const int cc = cb + j * 32;
    float4 hv = *(const float4*)&sH[row * 132 + cc];
    float4 gv = *(const float4*)&sG[row * 132 + cc];
    float4 bv = *(const float4*)&bias[c0 + cc];
    float4 xv = *(const float4*)&x [gbase + j * 32];
    float4 dv = *(const float4*)&xd[gbase + j * 32];
    f32x4 xh = {hv.x + bv.x, hv.y + bv.y, hv.z + bv.z, hv.w + bv.w};
    __builtin_nontemporal_store(xh, (f32x4*)&xhat[gbase + j * 32]);
    float e;
    e = xv.x - xh[0]; rsum = fmaf(e, e, rsum);
    e = xv.y - xh[1]; rsum = fmaf(e, e, rsum);
    e = xv.z - xh[2]; rsum = fmaf(e, e, rsum);
    e = xv.w - xh[3]; rsum = fmaf(e, e, rsum);
    e = dv.x - gv.x; ssum = fmaf(e, e, ssum);
    e = dv.y - gv.y; ssum = fmaf(e, e, ssum);
    e = dv.z - gv.z; ssum = fmaf(e, e, ssum);
    e = dv.w - gv.w; ssum = fmaf(e, e, ssum);
  }
#pragma unroll
  for (int off = 32; off > 0; off >>= 1) {
    rsum += __shfl_down(rsum, off);
    ssum += __shfl_down(ssum, off);
  }
  if (L == 0) { red[w * 2] = rsum; red[w * 2 + 1] = ssum; }
  __syncthreads();
  if (t == 0) {
    const int bid = blockIdx.y * gridDim.x + blockIdx.x;
    pr[bid] = red[0] + red[2] + red[4] + red[6];
    ps[bid] = red[1] + red[3] + red[5] + red[7];
  }
}

// ---------------------------------------------------------------------------
// K5: reduce all partials + write the 6 scalar outputs
// ---------------------------------------------------------------------------
__global__ __launch_bounds__(256) void finalize_kernel(
    const float* __restrict__ pr, const float* __restrict__ ps,
    const float* __restrict__ pe0, const float* __restrict__ pe1,
    const float* __restrict__ pe2, const float* __restrict__ coef,
    float* __restrict__ outp)
{
  __shared__ float sred[4][5];
  const int t = threadIdx.x, L = t & 63, w = t >> 6;
  float s[5] = {0.f, 0.f, 0.f, 0.f, 0.f};
  for (int i = t; i < 2048; i += 256) {   // pr/ps: 8192 floats
    float4 a = *(const float4*)&pr[i * 4];
    float4 b = *(const float4*)&ps[i * 4];
    s[0] += a.x + a.y + a.z + a.w;
    s[1] += b.x + b.y + b.z + b.w;
  }
  for (int i = t; i < 1024; i += 256) {   // pe*: 4096 floats
    float4 a = *(const float4*)&pe0[i * 4];
    float4 b = *(const float4*)&pe1[i * 4];
    float4 c = *(const float4*)&pe2[i * 4];
    s[2] += a.x + a.y + a.z + a.w;
    s[3] += b.x + b.y + b.z + b.w;
    s[4] += c.x + c.y + c.z + c.w;
  }
#pragma unroll
  for (int off = 32; off > 0; off >>= 1)
#pragma unroll
    for (int k = 0; k < 5; ++k) s[k] += __shfl_down(s[k], off);
  if (L == 0)
#pragma unroll
    for (int k = 0; k < 5; ++k) sred[w][k] = s[k];
  __syncthreads();
  if (t == 0) {
    float r[5];
#pragma unroll
    for (int k = 0; k < 5; ++k)
      r[k] = sred[0][k] + sred[1][k] + sred[2][k] + sred[3][k];
    outp[0] = r[2] * (1.0f / 16384.0f);      // loss_po
    outp[1] = r[3] * (1.0f / 16384.0f);      // loss_tr
    outp[2] = r[0] * (1.0f / 33554432.0f);   // recon
    outp[3] = r[1] * (1.0f / 33554432.0f);   // sindy_x
    outp[4] = r[4] * (1.0f / 49152.0f);      // sindy_z
    float l1 = 0.f;
    for (int i = 0; i < 21; ++i) l1 += fabsf(coef[i]);
    outp[5] = l1 * (1.0f / 21.0f);
  }
}

extern "C" void kernel_launch(void* const* d_in, const int* in_sizes, int n_in,
                              void* d_out, int out_size, void* d_ws, size_t ws_size,
                              hipStream_t stream) {
  (void)in_sizes; (void)n_in; (void)out_size; (void)ws_size;
  const float* x    = (const float*)d_in[0];
  const float* xd   = (const float*)d_in[1];
  const float* tr   = (const float*)d_in[2];
  const float* sz   = (const float*)d_in[3];
  const float* eW1  = (const float*)d_in[4];
  const float* eb1  = (const float*)d_in[5];
  const float* eW2  = (const float*)d_in[6];
  const float* eb2  = (const float*)d_in[7];
  const float* eW3  = (const float*)d_in[8];
  const float* eb3  = (const float*)d_in[9];
  const float* eW4  = (const float*)d_in[10];
  const float* eb4  = (const float*)d_in[11];
  const float* dW1  = (const float*)d_in[12];
  const float* db1  = (const float*)d_in[13];
  const float* dW2  = (const float*)d_in[14];
  const float* db2  = (const float*)d_in[15];
  const float* dW3  = (const float*)d_in[16];
  const float* db3  = (const float*)d_in[17];
  const float* dW4  = (const float*)d_in[18];
  const float* db4  = (const float*)d_in[19];
  const float* coef = (const float*)d_in[20];

  float* ws = (float*)d_ws;
  float* a1   = ws;                                       // 2097152 f32
  float* dz1  = ws + 2097152;                             // 2097152 f32
  float* zdp  = ws + 4194304;                             // 49152 f32
  unsigned short* h3b = (unsigned short*)(ws + 4243472);  // 2097152 bf16
  unsigned short* g3b = (unsigned short*)(ws + 5292048);  // 2097152 bf16
  unsigned short* Wb1 = (unsigned short*)(ws + 6340624);  // 262144 bf16
  unsigned short* Wb4 = (unsigned short*)(ws + 6471696);  // 262144 bf16
  // partial-sum arrays alias the Wb1 region (dead after enc1_mfma)
  float* pr  = ws + 6340624;                              // 8192 f32
  float* ps  = ws + 6348816;                              // 8192 f32
  float* pe0 = ws + 6357008;                              // 4096 f32
  float* pe1 = ws + 6361104;                              // 4096 f32
  float* pe2 = ws + 6365200;                              // 4096 f32

  float* z_out = (float*)d_out;                           // 16384*3
  float* xhat  = (float*)d_out + 49152;                   // 16384*2048
  float* scal  = (float*)d_out + 49152 + 33554432;        // 6 scalars

  wcvt_kernel<<<1024, 256, 0, stream>>>(eW1, dW4, Wb1, Wb4);
  enc1_mfma<<<1024, 256, 0, stream>>>(x, xd, tr, Wb1, eW1, eb1, a1, dz1);
  enc_small_kernel<<<4096, 256, 0, stream>>>(a1, dz1, eW2, eb2, eW3, eb3, eW4, eb4,
                                             coef, sz, tr, z_out, zdp, pe0, pe1, pe2);
  dec_small_kernel<<<4096, 256, 0, stream>>>(z_out, zdp, dW1, db1, dW2, db2, dW3, db3,
                                             h3b, g3b);
  dim3 g4(512, 16);
  dec4_mfma<<<g4, 256, 0, stream>>>(h3b, g3b, Wb4, db4, x, xd, xhat, pr, ps);
  finalize_kernel<<<1, 256, 0, stream>>>(pr, ps, pe0, pe1, pe2, coef, scal);
}

// Round 3
// 606.793 us; speedup vs baseline: 1.3609x; 1.0532x over previous
//
#include <hip/hip_runtime.h>
#include <hip/hip_bf16.h>
#include <math.h>

typedef __attribute__((ext_vector_type(8))) short short8;
typedef __attribute__((ext_vector_type(4))) float f32x4;

__device__ __forceinline__ float sigm(float v) { return 1.0f / (1.0f + expf(-v)); }
__device__ __forceinline__ unsigned short f2b(float f) {
  __hip_bfloat16 h = __float2bfloat16(f);
  return __builtin_bit_cast(unsigned short, h);
}

// ---------------------------------------------------------------------------
// K0: pre-convert eW1[:, :2048] -> Wb1 bf16 [128][2048], dW4 -> Wb4 bf16 [2048][128]
// ---------------------------------------------------------------------------
__global__ __launch_bounds__(256) void wcvt_kernel(
    const float* __restrict__ eW1, const float* __restrict__ dW4,
    unsigned short* __restrict__ Wb1, unsigned short* __restrict__ Wb4)
{
  int idx = blockIdx.x * 256 + threadIdx.x;   // 0..262143
  int o = idx >> 11, k = idx & 2047;
  Wb1[idx] = f2b(eW1[(size_t)o * 2049 + k]);
  Wb4[idx] = f2b(dW4[idx]);
}

// ---------------------------------------------------------------------------
// K1: MFMA dual GEMM: accx = x@W.T, accd = xd@W.T (bf16, fp32 acc)
// v3: depth-4 software pipeline, 24 loads in flight per wave. No LDS/barriers.
// ---------------------------------------------------------------------------
__global__ __launch_bounds__(256) void enc1_mfma(
    const float* __restrict__ x, const float* __restrict__ xd,
    const float* __restrict__ tr, const unsigned short* __restrict__ Wb,
    const float* __restrict__ Wfull, const float* __restrict__ bias,
    float* __restrict__ a1, float* __restrict__ dz1)
{
  const int t = threadIdx.x;
  const int w = t >> 6, L = t & 63, q = L >> 4, ln = L & 15;
  const int r0 = blockIdx.x * 16;
  const float* xA = x  + (size_t)(r0 + ln) * 2048;
  const float* dA = xd + (size_t)(r0 + ln) * 2048;
  const unsigned short* wB0 = Wb + (size_t)(w * 32 + ln) * 2048;
  const unsigned short* wB1 = Wb + (size_t)(w * 32 + 16 + ln) * 2048;

  f32x4 accx0 = (f32x4){0.f, 0.f, 0.f, 0.f};
  f32x4 accx1 = accx0, accd0 = accx0, accd1 = accx0;

#define LD(S, KT) \
    { const int kb_ = (KT) * 32 + q * 8; \
      S##x0 = *(const float4*)(xA + kb_); \
      S##x1 = *(const float4*)(xA + kb_ + 4); \
      S##d0 = *(const float4*)(dA + kb_); \
      S##d1 = *(const float4*)(dA + kb_ + 4); \
      S##b0 = *(const short8*)(wB0 + kb_); \
      S##b1 = *(const short8*)(wB1 + kb_); }

#define COMP(S) \
    { short8 ax_, ad_; \
      ax_[0] = (short)f2b(S##x0.x); ax_[1] = (short)f2b(S##x0.y); \
      ax_[2] = (short)f2b(S##x0.z); ax_[3] = (short)f2b(S##x0.w); \
      ax_[4] = (short)f2b(S##x1.x); ax_[5] = (short)f2b(S##x1.y); \
      ax_[6] = (short)f2b(S##x1.z); ax_[7] = (short)f2b(S##x1.w); \
      ad_[0] = (short)f2b(S##d0.x); ad_[1] = (short)f2b(S##d0.y); \
      ad_[2] = (short)f2b(S##d0.z); ad_[3] = (short)f2b(S##d0.w); \
      ad_[4] = (short)f2b(S##d1.x); ad_[5] = (short)f2b(S##d1.y); \
      ad_[6] = (short)f2b(S##d1.z); ad_[7] = (short)f2b(S##d1.w); \
      accx0 = __builtin_amdgcn_mfma_f32_16x16x32_bf16(ax_, S##b0, accx0, 0, 0, 0); \
      accx1 = __builtin_amdgcn_mfma_f32_16x16x32_bf16(ax_, S##b1, accx1, 0, 0, 0); \
      accd0 = __builtin_amdgcn_mfma_f32_16x16x32_bf16(ad_, S##b0, accd0, 0, 0, 0); \
      accd1 = __builtin_amdgcn_mfma_f32_16x16x32_bf16(ad_, S##b1, accd1, 0, 0, 0); }

  float4 F0x0, F0x1, F0d0, F0d1; short8 F0b0, F0b1;
  float4 F1x0, F1x1, F1d0, F1d1; short8 F1b0, F1b1;
  float4 F2x0, F2x1, F2d0, F2d1; short8 F2b0, F2b1;
  float4 F3x0, F3x1, F3d0, F3d1; short8 F3b0, F3b1;

  LD(F0, 0) LD(F1, 1) LD(F2, 2) LD(F3, 3)
  for (int kt = 0; kt < 60; kt += 4) {
    COMP(F0) LD(F0, kt + 4)
    COMP(F1) LD(F1, kt + 5)
    COMP(F2) LD(F2, kt + 6)
    COMP(F3) LD(F3, kt + 7)
  }
  COMP(F0) COMP(F1) COMP(F2) COMP(F3)
#undef LD
#undef COMP

  // epilogue: C[row = q*4 + r][col = w*32 + n*16 + ln]
#pragma unroll
  for (int r = 0; r < 4; ++r) {
    const int row = r0 + q * 4 + r;
    const float trv = tr[row];
    {
      const int col = w * 32 + ln;
      const float wl = Wfull[(size_t)col * 2049 + 2048];
      float p = accx0[r] + trv * wl + bias[col];
      float g = accd0[r] + trv * wl;
      float a = sigm(p);
      a1 [(size_t)row * 128 + col] = a;
      dz1[(size_t)row * 128 + col] = a * (1.f - a) * g;
    }
    {
      const int col = w * 32 + 16 + ln;
      const float wl = Wfull[(size_t)col * 2049 + 2048];
      float p = accx1[r] + trv * wl + bias[col];
      float g = accd1[r] + trv * wl;
      float a = sigm(p);
      a1 [(size_t)row * 128 + col] = a;
      dz1[(size_t)row * 128 + col] = a * (1.f - a) * g;
    }
  }
}

// ---------------------------------------------------------------------------
// K2: encoder layers 2-4. v2: 16 rows/block, k-outer multi-accumulator loops.
// ---------------------------------------------------------------------------
__global__ __launch_bounds__(256) void enc_small_kernel(
    const float* __restrict__ a1, const float* __restrict__ dz1,
    const float* __restrict__ W2, const float* __restrict__ b2,
    const float* __restrict__ W3, const float* __restrict__ b3,
    const float* __restrict__ W4, const float* __restrict__ b4,
    const float* __restrict__ coef, const float* __restrict__ size_in,
    const float* __restrict__ treat,
    float* __restrict__ z_out, float* __restrict__ zdp_out,
    float* __restrict__ pe0, float* __restrict__ pe1, float* __restrict__ pe2)
{
  __shared__ float sW2[64 * 129];
  __shared__ float sW3[32 * 65];
  __shared__ float sW4[96];
  __shared__ float sB2[64], sB3[32], sB4[3], sC[21];
  __shared__ __align__(16) float a1s[16 * 128], d1s[16 * 128];
  __shared__ float a2s[16 * 64],  d2s[16 * 64];
  __shared__ float a3s[16 * 32],  d3s[16 * 32];
  __shared__ float zs[48], zds[48];
  __shared__ float rowl[16][3];
  const int t = threadIdx.x;
  for (int i = t; i < 64 * 128; i += 256) sW2[(i >> 7) * 129 + (i & 127)] = W2[i];
  for (int i = t; i < 32 * 64;  i += 256) sW3[(i >> 6) * 65  + (i & 63)]  = W3[i];
  if (t < 96) sW4[t] = W4[t];
  if (t < 64) sB2[t] = b2[t];
  if (t < 32) sB3[t] = b3[t];
  if (t < 3)  sB4[t] = b4[t];
  if (t < 21) sC[t]  = coef[t];
  const int r0 = blockIdx.x * 16;
  {
    const float4* a1g = (const float4*)(a1  + (size_t)r0 * 128);
    const float4* d1g = (const float4*)(dz1 + (size_t)r0 * 128);
    float4* a1s4 = (float4*)a1s;
    float4* d1s4 = (float4*)d1s;
#pragma unroll
    for (int i = 0; i < 2; ++i) {
      a1s4[t + i * 256] = a1g[t + i * 256];
      d1s4[t + i * 256] = d1g[t + i * 256];
    }
  }
  __syncthreads();
  // layer 2: 16 rows x 64 outs; thread t -> o = t&63, rows rb, rb+4, rb+8, rb+12
  {
    const int o = t & 63, rb = t >> 6;
    float p[4] = {0.f, 0.f, 0.f, 0.f}, g[4] = {0.f, 0.f, 0.f, 0.f};
#pragma unroll 4
    for (int k = 0; k < 128; ++k) {
      const float wv = sW2[o * 129 + k];
#pragma unroll
      for (int u = 0; u < 4; ++u) {
        p[u] = fmaf(wv, a1s[(rb + u * 4) * 128 + k], p[u]);
        g[u] = fmaf(wv, d1s[(rb + u * 4) * 128 + k], g[u]);
      }
    }
#pragma unroll
    for (int u = 0; u < 4; ++u) {
      float a = sigm(p[u] + sB2[o]);
      a2s[(rb + u * 4) * 64 + o] = a;
      d2s[(rb + u * 4) * 64 + o] = a * (1.f - a) * g[u];
    }
  }
  __syncthreads();
  // layer 3: 16 rows x 32 outs; thread t -> o = t&31, rows r3, r3+8
  {
    const int o = t & 31, r3 = t >> 5;
    float p[2] = {0.f, 0.f}, g[2] = {0.f, 0.f};
#pragma unroll 4
    for (int k = 0; k < 64; ++k) {
      const float wv = sW3[o * 65 + k];
#pragma unroll
      for (int u = 0; u < 2; ++u) {
        p[u] = fmaf(wv, a2s[(r3 + u * 8) * 64 + k], p[u]);
        g[u] = fmaf(wv, d2s[(r3 + u * 8) * 64 + k], g[u]);
      }
    }
#pragma unroll
    for (int u = 0; u < 2; ++u) {
      float a = sigm(p[u] + sB3[o]);
      a3s[(r3 + u * 8) * 32 + o] = a;
      d3s[(r3 + u * 8) * 32 + o] = a * (1.f - a) * g[u];
    }
  }
  __syncthreads();
  if (t < 48) {
    const int r = t / 3, j = t % 3;
    float p = 0.f, g = 0.f;
#pragma unroll
    for (int k = 0; k < 32; ++k) {
      float wv = sW4[j * 32 + k];
      p = fmaf(wv, a3s[r * 32 + k], p);
      g = fmaf(wv, d3s[r * 32 + k], g);
    }
    float zv = p + sB4[j];
    zs [r * 3 + j] = zv;
    zds[r * 3 + j] = g;
    z_out[(size_t)(r0 + r) * 3 + j] = zv;
  }
  __syncthreads();
  if (t < 16) {
    const int r = t;
    float s = zs[r * 3 + 0], d = zs[r * 3 + 1], tt = zs[r * 3 + 2];
    float th[7] = {1.f, s, s * s, s * d, s * tt, s * s * d, s * s * tt};
    float sz = 0.f;
    for (int j = 0; j < 3; ++j) {
      float zp = 0.f;
#pragma unroll
      for (int i = 0; i < 7; ++i) zp = fmaf(th[i], sC[i * 3 + j], zp);
      zdp_out[(size_t)(r0 + r) * 3 + j] = zp;
      float e = zds[r * 3 + j] - zp;
      sz += e * e;
    }
    float e0 = s - size_in[r0 + r];
    float logit = tt;
    float trv = treat[r0 + r];
    float lt = fmaxf(logit, 0.f) + log1pf(expf(-fabsf(logit))) - logit * trv;
    rowl[r][0] = e0 * e0; rowl[r][1] = lt; rowl[r][2] = sz;
  }
  __syncthreads();
  if (t == 0) {
    float s0 = 0, s1 = 0, s2 = 0;
    for (int r = 0; r < 16; ++r) { s0 += rowl[r][0]; s1 += rowl[r][1]; s2 += rowl[r][2]; }
    pe0[blockIdx.x] = s0;
    pe1[blockIdx.x] = s1;
    pe2[blockIdx.x] = s2;
  }
}

// ---------------------------------------------------------------------------
// K3: decoder layers 1-3. v2: 16 rows/block, k-outer multi-accumulator loops.
// ---------------------------------------------------------------------------
__global__ __launch_bounds__(256) void dec_small_kernel(
    const float* __restrict__ z_in, const float* __restrict__ zdp,
    const float* __restrict__ W1, const float* __restrict__ b1,
    const float* __restrict__ W2, const float* __restrict__ b2,
    const float* __restrict__ W3, const float* __restrict__ b3,
    unsigned short* __restrict__ h3b, unsigned short* __restrict__ g3b)
{
  __shared__ float sW1[96], sB1[32];
  __shared__ float sW2[64 * 33], sB2[64];
  __shared__ float sW3[128 * 65], sB3[128];
  __shared__ float zr[48], zp[48];
  __shared__ float h1s[16 * 32], g1s[16 * 32];
  __shared__ float h2s[16 * 64], g2s[16 * 64];
  const int t = threadIdx.x;
  for (int i = t; i < 64 * 32;  i += 256) sW2[(i >> 5) * 33 + (i & 31)] = W2[i];
  for (int i = t; i < 128 * 64; i += 256) sW3[(i >> 6) * 65 + (i & 63)] = W3[i];
  if (t < 96)  sW1[t] = W1[t];
  if (t < 32)  sB1[t] = b1[t];
  if (t < 64)  sB2[t] = b2[t];
  if (t < 128) sB3[t] = b3[t];
  const int r0 = blockIdx.x * 16;
  if (t < 48) { zr[t] = z_in[(size_t)r0 * 3 + t]; zp[t] = zdp[(size_t)r0 * 3 + t]; }
  __syncthreads();
  // layer 1: 16 rows x 32 outs; thread -> o = t&31, rows r, r+8
  {
    const int o = t & 31, rb = t >> 5;
    float p[2], g[2];
#pragma unroll
    for (int u = 0; u < 2; ++u) {
      const int r = rb + u * 8;
      float pp = sB1[o], gg = 0.f;
#pragma unroll
      for (int k = 0; k < 3; ++k) {
        float wv = sW1[o * 3 + k];
        pp = fmaf(wv, zr[r * 3 + k], pp);
        gg = fmaf(wv, zp[r * 3 + k], gg);
      }
      p[u] = pp; g[u] = gg;
    }
#pragma unroll
    for (int u = 0; u < 2; ++u) {
      const int r = rb + u * 8;
      float h = sigm(p[u]);
      h1s[r * 32 + o] = h; g1s[r * 32 + o] = h * (1.f - h) * g[u];
    }
  }
  __syncthreads();
  // layer 2: 16 rows x 64 outs; thread -> o = t&63, rows rb, rb+4, rb+8, rb+12
  {
    const int o = t & 63, rb = t >> 6;
    float p[4], g[4];
#pragma unroll
    for (int u = 0; u < 4; ++u) { p[u] = sB2[o]; g[u] = 0.f; }
#pragma unroll 4
    for (int k = 0; k < 32; ++k) {
      const float wv = sW2[o * 33 + k];
#pragma unroll
      for (int u = 0; u < 4; ++u) {
        p[u] = fmaf(wv, h1s[(rb + u * 4) * 32 + k], p[u]);
        g[u] = fmaf(wv, g1s[(rb + u * 4) * 32 + k], g[u]);
      }
    }
#pragma unroll
    for (int u = 0; u < 4; ++u) {
      float h = sigm(p[u]);
      h2s[(rb + u * 4) * 64 + o] = h;
      g2s[(rb + u * 4) * 64 + o] = h * (1.f - h) * g[u];
    }
  }
  __syncthreads();
  // layer 3: 16 rows x 128 outs; thread -> o = t&127, rows rb2 + 2u (u<8)
  {
    const int o = t & 127, rb2 = t >> 7;
    float p[8], g[8];
#pragma unroll
    for (int u = 0; u < 8; ++u) { p[u] = sB3[o]; g[u] = 0.f; }
#pragma unroll 4
    for (int k = 0; k < 64; ++k) {
      const float wv = sW3[o * 65 + k];
#pragma unroll
      for (int u = 0; u < 8; ++u) {
        p[u] = fmaf(wv, h2s[(rb2 + u * 2) * 64 + k], p[u]);
        g[u] = fmaf(wv, g2s[(rb2 + u * 2) * 64 + k], g[u]);
      }
    }
#pragma unroll
    for (int u = 0; u < 8; ++u) {
      const int r = rb2 + u * 2;
      float h = sigm(p[u]);
      h3b[(size_t)(r0 + r) * 128 + o] = f2b(h);
      g3b[(size_t)(r0 + r) * 128 + o] = f2b(h * (1.f - h) * g[u]);
    }
  }
}

// ---------------------------------------------------------------------------
// K4: MFMA dual GEMM: xhat = h3@W4.T + b, xdp = g3@W4.T; fused recon/sindy_x.
// v3: epilogue x/xd/bias loads issued after frag loads, before transpose+barrier
// (latency hides under transpose + LDS reads).
// ---------------------------------------------------------------------------
__global__ __launch_bounds__(256, 2) void dec4_mfma(
    const unsigned short* __restrict__ h3b, const unsigned short* __restrict__ g3b,
    const unsigned short* __restrict__ Wb, const float* __restrict__ bias,
    const float* __restrict__ x, const float* __restrict__ xd,
    float* __restrict__ xhat, float* __restrict__ pr, float* __restrict__ ps)
{
  __shared__ float sH[32 * 132];
  __shared__ float sG[32 * 132];
  __shared__ float red[8];
  const int t = threadIdx.x, w = t >> 6, L = t & 63, q = L >> 4, ln = L & 15;
  const int r0 = blockIdx.x * 32, c0 = blockIdx.y * 128;

  f32x4 accH[2][2], accG[2][2];
#pragma unroll
  for (int m = 0; m < 2; ++m)
#pragma unroll
    for (int n = 0; n < 2; ++n) {
      accH[m][n] = (f32x4){0.f, 0.f, 0.f, 0.f};
      accG[m][n] = (f32x4){0.f, 0.f, 0.f, 0.f};
    }

  const size_t a0 = (size_t)(r0 + ln) * 128;
  const size_t a1r = (size_t)(r0 + 16 + ln) * 128;
  const size_t b0 = (size_t)(c0 + w * 32 + ln) * 128;
  const size_t b1 = (size_t)(c0 + w * 32 + 16 + ln) * 128;

#pragma unroll
  for (int ks = 0; ks < 4; ++ks) {
    const int kb = ks * 32 + q * 8;
    short8 ah0 = *(const short8*)&h3b[a0 + kb];
    short8 ah1 = *(const short8*)&h3b[a1r + kb];
    short8 ag0 = *(const short8*)&g3b[a0 + kb];
    short8 ag1 = *(const short8*)&g3b[a1r + kb];
    short8 bw0 = *(const short8*)&Wb[b0 + kb];
    short8 bw1 = *(const short8*)&Wb[b1 + kb];
    accH[0][0] = __builtin_amdgcn_mfma_f32_16x16x32_bf16(ah0, bw0, accH[0][0], 0, 0, 0);
    accH[0][1] = __builtin_amdgcn_mfma_f32_16x16x32_bf16(ah0, bw1, accH[0][1], 0, 0, 0);
    accH[1][0] = __builtin_amdgcn_mfma_f32_16x16x32_bf16(ah1, bw0, accH[1][0], 0, 0, 0);
    accH[1][1] = __builtin_amdgcn_mfma_f32_16x16x32_bf16(ah1, bw1, accH[1][1], 0, 0, 0);
    accG[0][0] = __builtin_amdgcn_mfma_f32_16x16x32_bf16(ag0, bw0, accG[0][0], 0, 0, 0);
    accG[0][1] = __builtin_amdgcn_mfma_f32_16x16x32_bf16(ag0, bw1, accG[0][1], 0, 0, 0);
    accG[1][0] = __builtin_amdgcn_mfma_f32_16x16x32_bf16(ag1, bw0, accG[1][0], 0, 0, 0);
    accG[1][1] = __builtin_amdgcn_mfma_f32_16x16x32_bf16(ag1, bw1, accG[1][1], 0, 0, 0);
  }

  // early-issue epilogue loads (independent of MFMA results)
  const int erow = t >> 3;
  const int ecb = (t & 7) * 4;
  const size_t gbase = (size_t)(r0 + erow) * 2048 + c0 + ecb;
  float4 exv0 = *(const float4*)&x [gbase];
  float4 exv1 = *(const float4*)&x [gbase + 32];
  float4 exv2 = *(const float4*)&x [gbase + 64];
  float4 exv3 = *(const float4*)&x [gbase + 96];
  float4 edv0 = *(const float4*)&xd[gbase];
  float4 edv1 = *(const float4*)&xd[gbase + 32];
  float4 edv2 = *(const float4*)&xd[gbase + 64];
  float4 edv3 = *(const float4*)&xd[gbase + 96];
  float4 ebv0 = *(const float4*)&bias[c0 + ecb];
  float4 ebv1 = *(const float4*)&bias[c0 + ecb + 32];
  float4 ebv2 = *(const float4*)&bias[c0 + ecb + 64];
  float4 ebv3 = *(const float4*)&bias[c0 + ecb + 96];

  // transpose accumulators to row-major f32 tiles in LDS
#pragma unroll
  for (int m = 0; m < 2; ++m)
#pragma unroll
    for (int n = 0; n < 2; ++n)
#pragma unroll
      for (int r = 0; r < 4; ++r) {
        const int rr = m * 16 + q * 4 + r;
        const int cc = w * 32 + n * 16 + ln;
        sH[rr * 132 + cc] = accH[m][n][r];
        sG[rr * 132 + cc] = accG[m][n][r];
      }
  __syncthreads();

  float rsum = 0.f, ssum = 0.f;
#define EPI(J, XV, DV, BV) \
  { \
    const int cc = ecb + (J) * 32; \
    float4 hv = *(const float4*)&sH[erow * 132 + cc]; \
    float4 gv = *(const float4*)&sG[erow * 132 + cc]; \
    f32x4 xh = {hv.x + BV.x, hv.y + BV.y, hv.z + BV.z, hv.w + BV.w}; \
    __builtin_nontemporal_store(xh, (f32x4*)&xhat[gbase + (J) * 32]); \
    float e; \
    e = XV.x - xh[0]; rsum = fmaf(e, e, rsum); \
    e = XV.y - xh[1]; rsum = fmaf(e, e, rsum); \
    e = XV.z - xh[2]; rsum = fmaf(e, e, rsum); \
    e = XV.w - xh[3]; rsum = fmaf(e, e, rsum); \
    e = DV.x - gv.x; ssum = fmaf(e, e, ssum); \
    e = DV.y - gv.y; ssum = fmaf(e, e, ssum); \
    e = DV.z - gv.z; ssum = fmaf(e, e, ssum); \
    e = DV.w - gv.w; ssum = fmaf(e, e, ssum); \
  }
  EPI(0, exv0, edv0, ebv0)
  EPI(1, exv1, edv1, ebv1)
  EPI(2, exv2, edv2, ebv2)
  EPI(3, exv3, edv3, ebv3)
#undef EPI

#pragma unroll
  for (int off = 32; off > 0; off >>= 1) {
    rsum += __shfl_down(rsum, off);
    ssum += __shfl_down(ssum, off);
  }
  if (L == 0) { red[w * 2] = rsum; red[w * 2 + 1] = ssum; }
  __syncthreads();
  if (t == 0) {
    const int bid = blockIdx.y * gridDim.x + blockIdx.x;
    pr[bid] = red[0] + red[2] + red[4] + red[6];
    ps[bid] = red[1] + red[3] + red[5] + red[7];
  }
}

// ---------------------------------------------------------------------------
// K5: reduce all partials + write the 6 scalar outputs
// ---------------------------------------------------------------------------
__global__ __launch_bounds__(256) void finalize_kernel(
    const float* __restrict__ pr, const float* __restrict__ ps,
    const float* __restrict__ pe0, const float* __restrict__ pe1,
    const float* __restrict__ pe2, const float* __restrict__ coef,
    float* __restrict__ outp)
{
  __shared__ float sred[4][5];
  const int t = threadIdx.x, L = t & 63, w = t >> 6;
  float s[5] = {0.f, 0.f, 0.f, 0.f, 0.f};
  for (int i = t; i < 2048; i += 256) {   // pr/ps: 8192 floats
    float4 a = *(const float4*)&pr[i * 4];
    float4 b = *(const float4*)&ps[i * 4];
    s[0] += a.x + a.y + a.z + a.w;
    s[1] += b.x + b.y + b.z + b.w;
  }
  if (t < 256) {                           // pe*: 1024 floats
    float4 a = *(const float4*)&pe0[t * 4];
    float4 b = *(const float4*)&pe1[t * 4];
    float4 c = *(const float4*)&pe2[t * 4];
    s[2] += a.x + a.y + a.z + a.w;
    s[3] += b.x + b.y + b.z + b.w;
    s[4] += c.x + c.y + c.z + c.w;
  }
#pragma unroll
  for (int off = 32; off > 0; off >>= 1)
#pragma unroll
    for (int k = 0; k < 5; ++k) s[k] += __shfl_down(s[k], off);
  if (L == 0)
#pragma unroll
    for (int k = 0; k < 5; ++k) sred[w][k] = s[k];
  __syncthreads();
  if (t == 0) {
    float r[5];
#pragma unroll
    for (int k = 0; k < 5; ++k)
      r[k] = sred[0][k] + sred[1][k] + sred[2][k] + sred[3][k];
    outp[0] = r[2] * (1.0f / 16384.0f);      // loss_po
    outp[1] = r[3] * (1.0f / 16384.0f);      // loss_tr
    outp[2] = r[0] * (1.0f / 33554432.0f);   // recon
    outp[3] = r[1] * (1.0f / 33554432.0f);   // sindy_x
    outp[4] = r[4] * (1.0f / 49152.0f);      // sindy_z
    float l1 = 0.f;
    for (int i = 0; i < 21; ++i) l1 += fabsf(coef[i]);
    outp[5] = l1 * (1.0f / 21.0f);
  }
}

extern "C" void kernel_launch(void* const* d_in, const int* in_sizes, int n_in,
                              void* d_out, int out_size, void* d_ws, size_t ws_size,
                              hipStream_t stream) {
  (void)in_sizes; (void)n_in; (void)out_size; (void)ws_size;
  const float* x    = (const float*)d_in[0];
  const float* xd   = (const float*)d_in[1];
  const float* tr   = (const float*)d_in[2];
  const float* sz   = (const float*)d_in[3];
  const float* eW1  = (const float*)d_in[4];
  const float* eb1  = (const float*)d_in[5];
  const float* eW2  = (const float*)d_in[6];
  const float* eb2  = (const float*)d_in[7];
  const float* eW3  = (const float*)d_in[8];
  const float* eb3  = (const float*)d_in[9];
  const float* eW4  = (const float*)d_in[10];
  const float* eb4  = (const float*)d_in[11];
  const float* dW1  = (const float*)d_in[12];
  const float* db1  = (const float*)d_in[13];
  const float* dW2  = (const float*)d_in[14];
  const float* db2  = (const float*)d_in[15];
  const float* dW3  = (const float*)d_in[16];
  const float* db3  = (const float*)d_in[17];
  const float* dW4  = (const float*)d_in[18];
  const float* db4  = (const float*)d_in[19];
  const float* coef = (const float*)d_in[20];

  float* ws = (float*)d_ws;
  float* a1   = ws;                                       // 2097152 f32
  float* dz1  = ws + 2097152;                             // 2097152 f32
  float* zdp  = ws + 4194304;                             // 49152 f32
  unsigned short* h3b = (unsigned short*)(ws + 4243472);  // 2097152 bf16
  unsigned short* g3b = (unsigned short*)(ws + 5292048);  // 2097152 bf16
  unsigned short* Wb1 = (unsigned short*)(ws + 6340624);  // 262144 bf16
  unsigned short* Wb4 = (unsigned short*)(ws + 6471696);  // 262144 bf16
  // partial-sum arrays alias the Wb1 region (dead after enc1_mfma)
  float* pr  = ws + 6340624;                              // 8192 f32
  float* ps  = ws + 6348816;                              // 8192 f32
  float* pe0 = ws + 6357008;                              // 1024 f32
  float* pe1 = ws + 6361104;                              // 1024 f32
  float* pe2 = ws + 6365200;                              // 1024 f32

  float* z_out = (float*)d_out;                           // 16384*3
  float* xhat  = (float*)d_out + 49152;                   // 16384*2048
  float* scal  = (float*)d_out + 49152 + 33554432;        // 6 scalars

  wcvt_kernel<<<1024, 256, 0, stream>>>(eW1, dW4, Wb1, Wb4);
  enc1_mfma<<<1024, 256, 0, stream>>>(x, xd, tr, Wb1, eW1, eb1, a1, dz1);
  enc_small_kernel<<<1024, 256, 0, stream>>>(a1, dz1, eW2, eb2, eW3, eb3, eW4, eb4,
                                             coef, sz, tr, z_out, zdp, pe0, pe1, pe2);
  dec_small_kernel<<<1024, 256, 0, stream>>>(z_out, zdp, dW1, db1, dW2, db2, dW3, db3,
                                             h3b, g3b);
  dim3 g4(512, 16);
  dec4_mfma<<<g4, 256, 0, stream>>>(h3b, g3b, Wb4, db4, x, xd, xhat, pr, ps);
  finalize_kernel<<<1, 256, 0, stream>>>(pr, ps, pe0, pe1, pe2, coef, scal);
}